// Round 2
// baseline (112.753 us; speedup 1.0000x reference)
//
#include <hip/hip_runtime.h>
#include <math.h>

// QIM1D: r = a*exp(-alpha*th)*sin(k*th)*cos(m*th) * |sum_i c_i*exp(i*w_i*th)|,
// minmax-normalized to [0,1], +0.5, broadcast to (B,1,L).
// L = 2^21, B = 4. Memory floor = 32 MiB output write (~5.3us @ 6.3TB/s).

#define L_TOT   2097152
#define NT      256
#define NB      2048          // NB*NT*4 == L_TOT exactly
#define EPSF    1e-8f

// ---------------------------------------------------------------------------
// Compute r for 4 consecutive grid points starting at j0.
// Uses one sincos init per oscillator + 3 rotation steps (angle addition),
// so only ~18 transcendentals per 4 elements instead of ~60.
// ---------------------------------------------------------------------------
__device__ __forceinline__ void compute_r4(
    int j0, float a, float alpha, float k, float m,
    const float* __restrict__ delta, const float* __restrict__ E,
    const float* __restrict__ uar, const float* __restrict__ uai,
    const float* __restrict__ ubr, const float* __restrict__ ubi,
    float r[4])
{
    const float h   = 1.0f / (float)(L_TOT - 1);
    const float th0 = (float)j0 * h;

    // coeffs = ub * conj(ua) / ((|ua|+eps)(|ub|+eps)), w_i = -(2E_i + delta_i)
    float cr[6], ci[6], w[6];
    {
        float na2 = 0.f, nb2 = 0.f;
        float ar[6], ai_[6], br[6], bi_[6];
#pragma unroll
        for (int i = 0; i < 6; ++i) {
            ar[i] = uar[i]; ai_[i] = uai[i]; br[i] = ubr[i]; bi_[i] = ubi[i];
            na2 = fmaf(ar[i], ar[i], fmaf(ai_[i], ai_[i], na2));
            nb2 = fmaf(br[i], br[i], fmaf(bi_[i], bi_[i], nb2));
        }
        const float s = 1.f / ((sqrtf(na2) + EPSF) * (sqrtf(nb2) + EPSF));
#pragma unroll
        for (int i = 0; i < 6; ++i) {
            cr[i] = (br[i] * ar[i] + bi_[i] * ai_[i]) * s;
            ci[i] = (bi_[i] * ar[i] - br[i] * ai_[i]) * s;
            w[i]  = -(2.f * E[i] + delta[i]);
        }
    }

    // oscillator states at th0 and per-step rotations (step h)
    float sk, ck, sm, cm, skh, ckh, smh, cmh;
    __sincosf(k * th0, &sk, &ck);
    __sincosf(m * th0, &sm, &cm);
    __sincosf(k * h,  &skh, &ckh);
    __sincosf(m * h,  &smh, &cmh);
    float e  = a * __expf(-alpha * th0);
    const float eh = __expf(-alpha * h);

    float sw[6], cw[6], swh[6], cwh[6];
#pragma unroll
    for (int i = 0; i < 6; ++i) {
        __sincosf(w[i] * th0, &sw[i], &cw[i]);
        __sincosf(w[i] * h,  &swh[i], &cwh[i]);
    }

#pragma unroll
    for (int t = 0; t < 4; ++t) {
        float re = 0.f, im = 0.f;
#pragma unroll
        for (int i = 0; i < 6; ++i) {
            re = fmaf(cr[i], cw[i], fmaf(-ci[i], sw[i], re));
            im = fmaf(cr[i], sw[i], fmaf( ci[i], cw[i], im));
        }
        const float S = sqrtf(fmaf(re, re, im * im));
        r[t] = e * sk * cm * S;

        if (t < 3) {  // advance all oscillators by h
            e *= eh;
            float ns, nc;
            ns = fmaf(sk, ckh,  ck * skh); nc = fmaf(ck, ckh, -sk * skh); sk = ns; ck = nc;
            ns = fmaf(sm, cmh,  cm * smh); nc = fmaf(cm, cmh, -sm * smh); sm = ns; cm = nc;
#pragma unroll
            for (int i = 0; i < 6; ++i) {
                ns = fmaf(sw[i], cwh[i],  cw[i] * swh[i]);
                nc = fmaf(cw[i], cwh[i], -sw[i] * swh[i]);
                sw[i] = ns; cw[i] = nc;
            }
        }
    }
}

__device__ __forceinline__ void block_minmax(float lmin, float lmax,
                                             float* out_min, float* out_max)
{
#pragma unroll
    for (int off = 32; off > 0; off >>= 1) {
        lmin = fminf(lmin, __shfl_down(lmin, off, 64));
        lmax = fmaxf(lmax, __shfl_down(lmax, off, 64));
    }
    __shared__ float smin[NT / 64], smax[NT / 64];
    const int lane = threadIdx.x & 63, wid = threadIdx.x >> 6;
    if (lane == 0) { smin[wid] = lmin; smax[wid] = lmax; }
    __syncthreads();
    if (threadIdx.x == 0) {
        float mn = smin[0], mx = smax[0];
#pragma unroll
        for (int i = 1; i < NT / 64; ++i) { mn = fminf(mn, smin[i]); mx = fmaxf(mx, smax[i]); }
        *out_min = mn; *out_max = mx;
    }
}

// Pass 1: per-block min/max partials -> ws[0..NB) mins, ws[NB..2NB) maxes
__global__ __launch_bounds__(NT) void qim_minmax(
    const float* __restrict__ a_p, const float* __restrict__ alpha_p,
    const float* __restrict__ k_p, const float* __restrict__ m_p,
    const float* __restrict__ delta, const float* __restrict__ E,
    const float* __restrict__ uar, const float* __restrict__ uai,
    const float* __restrict__ ubr, const float* __restrict__ ubi,
    float* __restrict__ partials)
{
    const int gid = blockIdx.x * NT + threadIdx.x;
    float r[4];
    compute_r4(gid * 4, *a_p, *alpha_p, *k_p, *m_p,
               delta, E, uar, uai, ubr, ubi, r);
    const float lmin = fminf(fminf(r[0], r[1]), fminf(r[2], r[3]));
    const float lmax = fmaxf(fmaxf(r[0], r[1]), fmaxf(r[2], r[3]));
    float mn, mx;
    block_minmax(lmin, lmax, &mn, &mx);
    if (threadIdx.x == 0) {
        partials[blockIdx.x]      = mn;
        partials[NB + blockIdx.x] = mx;
    }
}

// Pass 2: fold NB partial pairs -> gout[0]=gmin, gout[1]=1/(gmax-gmin+eps)
__global__ __launch_bounds__(NT) void qim_reduce(
    const float* __restrict__ partials, float* __restrict__ gout)
{
    float lmin = 3.402823466e38f, lmax = -3.402823466e38f;
    for (int i = threadIdx.x; i < NB; i += NT) {
        lmin = fminf(lmin, partials[i]);
        lmax = fmaxf(lmax, partials[NB + i]);
    }
    float mn, mx;
    block_minmax(lmin, lmax, &mn, &mx);
    if (threadIdx.x == 0) {
        gout[0] = mn;
        gout[1] = 1.0f / (mx - mn + EPSF);
    }
}

// Pass 3: recompute r, normalize, broadcast-write B copies (float4 stores)
__global__ __launch_bounds__(NT) void qim_write(
    const float* __restrict__ a_p, const float* __restrict__ alpha_p,
    const float* __restrict__ k_p, const float* __restrict__ m_p,
    const float* __restrict__ delta, const float* __restrict__ E,
    const float* __restrict__ uar, const float* __restrict__ uai,
    const float* __restrict__ ubr, const float* __restrict__ ubi,
    const float* __restrict__ gout, float* __restrict__ out, int copies)
{
    const int gid = blockIdx.x * NT + threadIdx.x;
    const int j0  = gid * 4;
    float r[4];
    compute_r4(j0, *a_p, *alpha_p, *k_p, *m_p,
               delta, E, uar, uai, ubr, ubi, r);
    const float gmin = gout[0], inv = gout[1];
    float4 o;
    o.x = fmaf(r[0] - gmin, inv, 0.5f);
    o.y = fmaf(r[1] - gmin, inv, 0.5f);
    o.z = fmaf(r[2] - gmin, inv, 0.5f);
    o.w = fmaf(r[3] - gmin, inv, 0.5f);
    for (int b = 0; b < copies; ++b)
        *reinterpret_cast<float4*>(out + (size_t)b * L_TOT + j0) = o;
}

extern "C" void kernel_launch(void* const* d_in, const int* in_sizes, int n_in,
                              void* d_out, int out_size, void* d_ws, size_t ws_size,
                              hipStream_t stream)
{
    const float* a_p     = (const float*)d_in[0];
    const float* alpha_p = (const float*)d_in[1];
    const float* k_p     = (const float*)d_in[2];
    const float* m_p     = (const float*)d_in[3];
    const float* delta   = (const float*)d_in[4];
    const float* E       = (const float*)d_in[5];
    const float* uar     = (const float*)d_in[6];
    const float* uai     = (const float*)d_in[7];
    const float* ubr     = (const float*)d_in[8];
    const float* ubi     = (const float*)d_in[9];
    // d_in[10] = B, d_in[11] = L (device ints); shapes are fixed by the bench:
    // L == L_TOT, B == out_size / L_TOT.
    float* out = (float*)d_out;
    float* wsf = (float*)d_ws;
    float* partials = wsf;            // 2*NB floats
    float* gout     = wsf + 2 * NB;   // 2 floats

    const int copies = out_size / L_TOT;  // == 4

    qim_minmax<<<NB, NT, 0, stream>>>(a_p, alpha_p, k_p, m_p, delta, E,
                                      uar, uai, ubr, ubi, partials);
    qim_reduce<<<1, NT, 0, stream>>>(partials, gout);
    qim_write<<<NB, NT, 0, stream>>>(a_p, alpha_p, k_p, m_p, delta, E,
                                     uar, uai, ubr, ubi, gout, out, copies);
}

// Round 5
// 112.052 us; speedup vs baseline: 1.0063x; 1.0063x over previous
//
#include <hip/hip_runtime.h>
#include <math.h>

// QIM1D: r = a*exp(-alpha*th)*sin(k*th)*cos(m*th) * |sum_i c_i*exp(i*w_i*th)|,
// minmax-normalized to [0,1], +0.5, broadcast to (B,1,L).
// L = 2^21, B = 4. Memory floor = 32 MiB output write (~5.3us @ 6.3TB/s).
//
// R2 lesson: __sincosf routes to precise __ocml_sincos_f32 (~100 inst each);
// 14 of them per thread made both compute passes VALU-bound at ~10x the model.
// Fix: native __sinf/__cosf/__expf (v_sin_f32 etc.) + hoist all uniform math
// (coeffs, frequencies, step rotations) into a 1-thread setup kernel -> ws.

#define L_TOT   2097152
#define NT      256
#define NB      2048          // NB*NT*4 == L_TOT exactly
#define EPSF    1e-8f

// ws float layout
#define WS_CR    0    // [6]
#define WS_CI    6    // [6]
#define WS_W     12   // [6]
#define WS_SKH   18
#define WS_CKH   19
#define WS_SMH   20
#define WS_CMH   21
#define WS_EH    22
#define WS_A     23
#define WS_ALPHA 24
#define WS_K     25
#define WS_M     26
#define WS_SWH   27   // [6]
#define WS_CWH   33   // [6]
#define WS_NCST  40
#define WS_PART  64                 // partials: [NB] mins, [NB] maxes
#define WS_GOUT  (WS_PART + 2*NB)   // gmin, inv_range

// ---------------------------------------------------------------------------
// Setup: all thread-uniform math, computed once (1 thread, precise libm).
// ---------------------------------------------------------------------------
__global__ __launch_bounds__(64) void qim_setup(
    const float* __restrict__ a_p, const float* __restrict__ alpha_p,
    const float* __restrict__ k_p, const float* __restrict__ m_p,
    const float* __restrict__ delta, const float* __restrict__ E,
    const float* __restrict__ uar, const float* __restrict__ uai,
    const float* __restrict__ ubr, const float* __restrict__ ubi,
    float* __restrict__ cst)
{
    if (threadIdx.x != 0) return;
    const float h = 1.0f / (float)(L_TOT - 1);

    float na2 = 0.f, nb2 = 0.f;
    for (int i = 0; i < 6; ++i) {
        na2 = fmaf(uar[i], uar[i], fmaf(uai[i], uai[i], na2));
        nb2 = fmaf(ubr[i], ubr[i], fmaf(ubi[i], ubi[i], nb2));
    }
    const float s = 1.f / ((sqrtf(na2) + EPSF) * (sqrtf(nb2) + EPSF));
    for (int i = 0; i < 6; ++i) {
        // coeffs = ub * conj(ua), normalized
        cst[WS_CR + i] = (ubr[i] * uar[i] + ubi[i] * uai[i]) * s;
        cst[WS_CI + i] = (ubi[i] * uar[i] - ubr[i] * uai[i]) * s;
        const float w  = -(2.f * E[i] + delta[i]);
        cst[WS_W + i]  = w;
        cst[WS_SWH + i] = sinf(w * h);
        cst[WS_CWH + i] = cosf(w * h);
    }
    const float k = *k_p, m = *m_p, alpha = *alpha_p;
    cst[WS_SKH] = sinf(k * h);  cst[WS_CKH] = cosf(k * h);
    cst[WS_SMH] = sinf(m * h);  cst[WS_CMH] = cosf(m * h);
    cst[WS_EH]  = expf(-alpha * h);
    cst[WS_A] = *a_p; cst[WS_ALPHA] = alpha; cst[WS_K] = k; cst[WS_M] = m;
}

// ---------------------------------------------------------------------------
// r for 4 consecutive grid points from j0: native-trans init (8 sincos + 1
// exp) + 3 angle-addition rotation steps. All cst[] loads are uniform.
// ---------------------------------------------------------------------------
__device__ __forceinline__ void compute_r4(
    const float* __restrict__ cst, int j0, float r[4])
{
    const float h   = 1.0f / (float)(L_TOT - 1);
    const float th0 = (float)j0 * h;

    const float skh = cst[WS_SKH], ckh = cst[WS_CKH];
    const float smh = cst[WS_SMH], cmh = cst[WS_CMH];
    const float eh  = cst[WS_EH];

    float sk = __sinf(cst[WS_K] * th0), ck = __cosf(cst[WS_K] * th0);
    float sm = __sinf(cst[WS_M] * th0), cm = __cosf(cst[WS_M] * th0);
    float e  = cst[WS_A] * __expf(-cst[WS_ALPHA] * th0);

    float sw[6], cw[6];
#pragma unroll
    for (int i = 0; i < 6; ++i) {
        const float ph = cst[WS_W + i] * th0;
        sw[i] = __sinf(ph);
        cw[i] = __cosf(ph);
    }

#pragma unroll
    for (int t = 0; t < 4; ++t) {
        float re = 0.f, im = 0.f;
#pragma unroll
        for (int i = 0; i < 6; ++i) {
            const float cr = cst[WS_CR + i], ci = cst[WS_CI + i];
            re = fmaf(cr, cw[i], fmaf(-ci, sw[i], re));
            im = fmaf(cr, sw[i], fmaf( ci, cw[i], im));
        }
        const float S = __fsqrt_rn(fmaf(re, re, im * im));
        r[t] = e * sk * cm * S;

        if (t < 3) {  // advance all oscillators by h
            e *= eh;
            float ns, nc;
            ns = fmaf(sk, ckh,  ck * skh); nc = fmaf(ck, ckh, -sk * skh); sk = ns; ck = nc;
            ns = fmaf(sm, cmh,  cm * smh); nc = fmaf(cm, cmh, -sm * smh); sm = ns; cm = nc;
#pragma unroll
            for (int i = 0; i < 6; ++i) {
                const float swh = cst[WS_SWH + i], cwh = cst[WS_CWH + i];
                ns = fmaf(sw[i], cwh,  cw[i] * swh);
                nc = fmaf(cw[i], cwh, -sw[i] * swh);
                sw[i] = ns; cw[i] = nc;
            }
        }
    }
}

__device__ __forceinline__ void block_minmax(float lmin, float lmax,
                                             float* out_min, float* out_max)
{
#pragma unroll
    for (int off = 32; off > 0; off >>= 1) {
        lmin = fminf(lmin, __shfl_down(lmin, off, 64));
        lmax = fmaxf(lmax, __shfl_down(lmax, off, 64));
    }
    __shared__ float smin[NT / 64], smax[NT / 64];
    const int lane = threadIdx.x & 63, wid = threadIdx.x >> 6;
    if (lane == 0) { smin[wid] = lmin; smax[wid] = lmax; }
    __syncthreads();
    if (threadIdx.x == 0) {
        float mn = smin[0], mx = smax[0];
#pragma unroll
        for (int i = 1; i < NT / 64; ++i) { mn = fminf(mn, smin[i]); mx = fmaxf(mx, smax[i]); }
        *out_min = mn; *out_max = mx;
    }
}

// Pass 1: per-block min/max partials
__global__ __launch_bounds__(NT) void qim_minmax(
    const float* __restrict__ cst, float* __restrict__ partials)
{
    const int gid = blockIdx.x * NT + threadIdx.x;
    float r[4];
    compute_r4(cst, gid * 4, r);
    const float lmin = fminf(fminf(r[0], r[1]), fminf(r[2], r[3]));
    const float lmax = fmaxf(fmaxf(r[0], r[1]), fmaxf(r[2], r[3]));
    float mn, mx;
    block_minmax(lmin, lmax, &mn, &mx);
    if (threadIdx.x == 0) {
        partials[blockIdx.x]      = mn;
        partials[NB + blockIdx.x] = mx;
    }
}

// Pass 2: fold NB partial pairs -> gout[0]=gmin, gout[1]=1/(gmax-gmin+eps)
__global__ __launch_bounds__(NT) void qim_reduce(
    const float* __restrict__ partials, float* __restrict__ gout)
{
    float lmin = 3.402823466e38f, lmax = -3.402823466e38f;
    for (int i = threadIdx.x; i < NB; i += NT) {
        lmin = fminf(lmin, partials[i]);
        lmax = fmaxf(lmax, partials[NB + i]);
    }
    float mn, mx;
    block_minmax(lmin, lmax, &mn, &mx);
    if (threadIdx.x == 0) {
        gout[0] = mn;
        gout[1] = 1.0f / (mx - mn + EPSF);
    }
}

// Pass 3: recompute r, normalize, broadcast-write B copies (float4 stores)
__global__ __launch_bounds__(NT) void qim_write(
    const float* __restrict__ cst, const float* __restrict__ gout,
    float* __restrict__ out, int copies)
{
    const int gid = blockIdx.x * NT + threadIdx.x;
    const int j0  = gid * 4;
    float r[4];
    compute_r4(cst, j0, r);
    const float gmin = gout[0], inv = gout[1];
    float4 o;
    o.x = fmaf(r[0] - gmin, inv, 0.5f);
    o.y = fmaf(r[1] - gmin, inv, 0.5f);
    o.z = fmaf(r[2] - gmin, inv, 0.5f);
    o.w = fmaf(r[3] - gmin, inv, 0.5f);
    for (int b = 0; b < copies; ++b)
        *reinterpret_cast<float4*>(out + (size_t)b * L_TOT + j0) = o;
}

extern "C" void kernel_launch(void* const* d_in, const int* in_sizes, int n_in,
                              void* d_out, int out_size, void* d_ws, size_t ws_size,
                              hipStream_t stream)
{
    const float* a_p     = (const float*)d_in[0];
    const float* alpha_p = (const float*)d_in[1];
    const float* k_p     = (const float*)d_in[2];
    const float* m_p     = (const float*)d_in[3];
    const float* delta   = (const float*)d_in[4];
    const float* E       = (const float*)d_in[5];
    const float* uar     = (const float*)d_in[6];
    const float* uai     = (const float*)d_in[7];
    const float* ubr     = (const float*)d_in[8];
    const float* ubi     = (const float*)d_in[9];
    float* out = (float*)d_out;
    float* wsf = (float*)d_ws;

    float* cst      = wsf;
    float* partials = wsf + WS_PART;
    float* gout     = wsf + WS_GOUT;

    const int copies = out_size / L_TOT;  // == 4

    qim_setup<<<1, 64, 0, stream>>>(a_p, alpha_p, k_p, m_p, delta, E,
                                    uar, uai, ubr, ubi, cst);
    qim_minmax<<<NB, NT, 0, stream>>>(cst, partials);
    qim_reduce<<<1, NT, 0, stream>>>(partials, gout);
    qim_write<<<NB, NT, 0, stream>>>(cst, gout, out, copies);
}